// Round 1
// baseline (125.066 us; speedup 1.0000x reference)
//
#include <hip/hip_runtime.h>

#define THREADS 256
#define WAVE 64

// Stage 1: each thread handles 4 consecutive samples (float4/int4 loads on
// every stream -> 16B/lane coalesced). Four fp32 accumulators, wave shuffle
// reduce, cross-wave LDS reduce, one float4 partial per block.
__global__ __launch_bounds__(THREADS) void loss_reduce(
    const float4* __restrict__ pred4,   // 2 float4 per 4 samples
    const float4* __restrict__ tgt4,
    const float4* __restrict__ prev4,
    const int4*   __restrict__ dt4,
    const int4*   __restrict__ pv4,
    float4* __restrict__ partials,
    int n4)
{
    int i = blockIdx.x * THREADS + threadIdx.x;
    float s0 = 0.f, s1 = 0.f, s2 = 0.f, s3 = 0.f;
    if (i < n4) {
        float4 p0 = pred4[2 * i];
        float4 p1 = pred4[2 * i + 1];
        float4 tg = tgt4[i];
        float4 pp = prev4[i];
        int4   dt = dt4[i];
        int4   pv = pv4[i];

        float lo[4] = {p0.x, p0.z, p1.x, p1.z};
        float up[4] = {p0.y, p0.w, p1.y, p1.w};
        float tga[4] = {tg.x, tg.y, tg.z, tg.w};
        float ppa[4] = {pp.x, pp.y, pp.z, pp.w};
        int dta[4] = {dt.x, dt.y, dt.z, dt.w};
        int pva[4] = {pv.x, pv.y, pv.z, pv.w};

#pragma unroll
        for (int j = 0; j < 4; ++j) {
            float c = 0.5f * (lo[j] + up[j]);
            float d = tga[j] - c;
            s0 += d * d;                       // center_loss numerator
            s1 += up[j] - lo[j];               // width_loss numerator
            s2 += fmaxf(lo[j] - up[j], 0.0f);  // valid_penalty numerator
            float diff = c - ppa[j];
            float pen = (pva[j] == 0) ? fmaxf(diff, 0.0f) : fmaxf(-diff, 0.0f);
            s3 += (dta[j] != 0) ? pen : 0.0f;  // direction_penalty
        }
    }

#pragma unroll
    for (int off = 32; off > 0; off >>= 1) {
        s0 += __shfl_down(s0, off, WAVE);
        s1 += __shfl_down(s1, off, WAVE);
        s2 += __shfl_down(s2, off, WAVE);
        s3 += __shfl_down(s3, off, WAVE);
    }

    __shared__ float4 smem[THREADS / WAVE];
    int wave = threadIdx.x >> 6;
    if ((threadIdx.x & 63) == 0) smem[wave] = make_float4(s0, s1, s2, s3);
    __syncthreads();
    if (threadIdx.x == 0) {
        float4 acc = smem[0];
#pragma unroll
        for (int w = 1; w < THREADS / WAVE; ++w) {
            acc.x += smem[w].x; acc.y += smem[w].y;
            acc.z += smem[w].z; acc.w += smem[w].w;
        }
        partials[blockIdx.x] = acc;
    }
}

// Stage 2: single block combines the per-block partials (plus any scalar tail
// if n % 4 != 0 — not the case here, but defensive) and applies the weights.
__global__ __launch_bounds__(THREADS) void loss_final(
    const float4* __restrict__ partials, int nblocks,
    const float* __restrict__ pred, const float* __restrict__ tgt,
    const float* __restrict__ prev, const int* __restrict__ dt,
    const int* __restrict__ pvv,
    int tail_start, int n,
    float* __restrict__ out)
{
    float s0 = 0.f, s1 = 0.f, s2 = 0.f, s3 = 0.f;
    for (int t = threadIdx.x; t < nblocks; t += THREADS) {
        float4 p = partials[t];
        s0 += p.x; s1 += p.y; s2 += p.z; s3 += p.w;
    }
    if (threadIdx.x == 0) {
        for (int i = tail_start; i < n; ++i) {
            float lo = pred[2 * i], up = pred[2 * i + 1];
            float c = 0.5f * (lo + up);
            float d = tgt[i] - c;
            s0 += d * d; s1 += up - lo; s2 += fmaxf(lo - up, 0.f);
            float diff = c - prev[i];
            float pen = (pvv[i] == 0) ? fmaxf(diff, 0.f) : fmaxf(-diff, 0.f);
            s3 += (dt[i] != 0) ? pen : 0.f;
        }
    }

#pragma unroll
    for (int off = 32; off > 0; off >>= 1) {
        s0 += __shfl_down(s0, off, WAVE);
        s1 += __shfl_down(s1, off, WAVE);
        s2 += __shfl_down(s2, off, WAVE);
        s3 += __shfl_down(s3, off, WAVE);
    }

    __shared__ float4 smem[THREADS / WAVE];
    int wave = threadIdx.x >> 6;
    if ((threadIdx.x & 63) == 0) smem[wave] = make_float4(s0, s1, s2, s3);
    __syncthreads();
    if (threadIdx.x == 0) {
        float4 acc = smem[0];
#pragma unroll
        for (int w = 1; w < THREADS / WAVE; ++w) {
            acc.x += smem[w].x; acc.y += smem[w].y;
            acc.z += smem[w].z; acc.w += smem[w].w;
        }
        float inv_n = 1.0f / (float)n;
        out[0] = (1.5f * acc.x + 0.1f * acc.y + 10.0f * acc.z + 0.5f * acc.w) * inv_n;
    }
}

extern "C" void kernel_launch(void* const* d_in, const int* in_sizes, int n_in,
                              void* d_out, int out_size, void* d_ws, size_t ws_size,
                              hipStream_t stream) {
    const float* pred   = (const float*)d_in[0];
    const float* target = (const float*)d_in[1];
    const float* prev   = (const float*)d_in[2];
    const int*   dt     = (const int*)d_in[3];
    const int*   pv     = (const int*)d_in[4];
    float* out = (float*)d_out;

    int n  = in_sizes[3];          // B (delta_time is (B,))
    int n4 = n >> 2;               // groups of 4 samples
    int nblocks = (n4 + THREADS - 1) / THREADS;   // 4096 for B=4194304

    float4* partials = (float4*)d_ws;             // 4096 * 16B = 64 KB

    loss_reduce<<<nblocks, THREADS, 0, stream>>>(
        (const float4*)pred, (const float4*)target, (const float4*)prev,
        (const int4*)dt, (const int4*)pv, partials, n4);

    loss_final<<<1, THREADS, 0, stream>>>(
        partials, nblocks, pred, target, prev, dt, pv, n4 * 4, n, out);
}